// Round 18
// baseline (902.355 us; speedup 1.0000x reference)
//
#include <hip/hip_runtime.h>
#include <hip/hip_bf16.h>

#define TPB 256
#define CHUNK 8
#define LOG2E 1.4426950408889634f

// v_exp_f32 is natively 2^x on CDNA; __builtin_amdgcn_exp2f lowers to it.
__device__ __forceinline__ float fast_exp2(float x) {
  return __builtin_amdgcn_exp2f(x);
}

// ---------------------------------------------------------------------------
// Problem constants (from reference): H=4 heads, C=64, EMB=128, G=64 groups.
// N, E taken from in_sizes at launch.
// ---------------------------------------------------------------------------

__global__ void gather_emb_k(const int* __restrict__ x, const float* __restrict__ emb,
                             float* __restrict__ h0, int n) {
  int idx = blockIdx.x * TPB + threadIdx.x;
  if (idx >= n * 128) return;
  int node = idx >> 7, k = idx & 127;
  h0[idx] = emb[x[node * 2] * 128 + k];
}

__global__ void edge_hist_k(const int* __restrict__ ei, int* __restrict__ deg, int E, int n) {
  int e = blockIdx.x * TPB + threadIdx.x;
  if (e >= E + n) return;
  int dst = (e < E) ? ei[E + e] : (e - E);
  atomicAdd(&deg[dst], 1);
}

__global__ void scan_block_k(const int* __restrict__ deg, int* __restrict__ row_ptr,
                             int* __restrict__ bsum, int n) {
  __shared__ int buf[TPB];
  int t = threadIdx.x, base = blockIdx.x * TPB;
  int v = (base + t < n) ? deg[base + t] : 0;
  buf[t] = v;
  __syncthreads();
  for (int off = 1; off < TPB; off <<= 1) {
    int xv = (t >= off) ? buf[t - off] : 0;
    __syncthreads();
    buf[t] += xv;
    __syncthreads();
  }
  if (base + t < n) row_ptr[base + t + 1] = buf[t];
  if (t == TPB - 1) bsum[blockIdx.x] = buf[t];
}

__global__ void scan_bsum_k(int* __restrict__ bsum, int B) {
  __shared__ int buf[TPB];
  int t = threadIdx.x;
  int v = (t < B) ? bsum[t] : 0;
  buf[t] = v;
  __syncthreads();
  for (int off = 1; off < TPB; off <<= 1) {
    int xv = (t >= off) ? buf[t - off] : 0;
    __syncthreads();
    buf[t] += xv;
    __syncthreads();
  }
  if (t < B) bsum[t] = buf[t] - v;  // exclusive block offsets
}

__global__ void scan_add_k(int* __restrict__ row_ptr, const int* __restrict__ bsum, int n) {
  int idx = blockIdx.x * TPB + threadIdx.x;
  if (idx == 0) row_ptr[0] = 0;
  if (idx < n) row_ptr[idx + 1] += bsum[idx >> 8];
}

__global__ void edge_scatter_k(const int* __restrict__ ei, const int* __restrict__ row_ptr,
                               int* __restrict__ cursor, int* __restrict__ csr_src,
                               int E, int n) {
  int e = blockIdx.x * TPB + threadIdx.x;
  if (e >= E + n) return;
  int src, dst;
  if (e < E) { src = ei[e]; dst = ei[E + e]; }
  else       { src = e - E; dst = e - E; }
  int pos = atomicAdd(&cursor[dst], 1);
  csr_src[row_ptr[dst] + pos] = src;
}

// hW[n][256] = h[n][K] @ W[K][256].  16 nodes x 256 cols per block.
// h loads are block-uniform (scalar path); W loads coalesced across threads.
template <int K>
__global__ __launch_bounds__(TPB) void gemm_hw_k(const float* __restrict__ h,
                                                 const float* __restrict__ W,
                                                 float* __restrict__ hW, int n) {
  int t = threadIdx.x;
  int n0 = blockIdx.x * 16;
  float acc[16];
#pragma unroll
  for (int i = 0; i < 16; i++) acc[i] = 0.f;
  const float* hb = h + (size_t)n0 * K;
  for (int k0 = 0; k0 < K; k0 += 8) {
    float wv[8];
#pragma unroll
    for (int kk = 0; kk < 8; kk++) wv[kk] = W[(k0 + kk) * 256 + t];
#pragma unroll
    for (int i = 0; i < 16; i++) {
#pragma unroll
      for (int kk = 0; kk < 8; kk++)
        acc[i] = fmaf(hb[i * K + k0 + kk], wv[kk], acc[i]);
    }
  }
  float* outp = hW + (size_t)n0 * 256 + t;
#pragma unroll
  for (int i = 0; i < 16; i++)
    if (n0 + i < n) outp[i * 256] = acc[i];
}

// a_src[n][h] = (sum_c hW[n][h*64+c]*as[h][c]) * log2(e); a_dst likewise.
// log2-scaling commutes with leaky-relu (positive scale), so the softmax
// in gat_agg_k can use raw v_exp_f32 (exp2) with identical alphas.
__global__ void attn_coef_k(const float* __restrict__ hW, const float* __restrict__ as,
                            const float* __restrict__ ad, float* __restrict__ a_srcv,
                            float* __restrict__ a_dstv, int n) {
  int idx = blockIdx.x * TPB + threadIdx.x;
  if (idx >= n * 4) return;
  int node = idx >> 2, hh = idx & 3;
  const float* row = hW + (size_t)node * 256 + hh * 64;
  const float* asr = as + hh * 64;
  const float* adr = ad + hh * 64;
  float s = 0.f, d = 0.f;
#pragma unroll 8
  for (int c = 0; c < 64; c++) {
    float v = row[c];
    s = fmaf(v, asr[c], s);
    d = fmaf(v, adr[c], d);
  }
  a_srcv[idx] = s * LOG2E;
  a_dstv[idx] = d * LOG2E;
}

// One WAVE per dst node (4 nodes per 256-thread block, no LDS, no barriers).
// Lane l owns cols [4l,4l+3]; head = l>>4 (4l == (l>>4)*64 + (l&15)*4).
// CHUNK-deep pipelined gathers + max-form online softmax in log2 domain:
//   mn = max(m,e); sc = exp2(m-mn); p = exp2(e-mn)   (one v_exp each, no selects)
// Cross-head mean via shfl_xor butterfly (masks 16,32); lanes 0-15 store float4.
__global__ __launch_bounds__(TPB) void gat_agg_k(
    const float* __restrict__ hW, const float* __restrict__ a_srcv,
    const float* __restrict__ a_dstv, const int* __restrict__ row_ptr,
    const int* __restrict__ csr_src, const float* __restrict__ bias,
    float* __restrict__ h_out, int n) {
  int w = threadIdx.x >> 6;            // wave 0..3 in block
  int node = blockIdx.x * 4 + w;
  if (node >= n) return;               // wave-uniform; no barriers in kernel
  int l = threadIdx.x & 63;
  int hh = l >> 4;                     // head
  int beg = row_ptr[node], end = row_ptr[node + 1];
  float ad = a_dstv[node * 4 + hh];    // log2-domain

  float m = -1e30f, ssum = 0.f;
  float ax = 0.f, ay = 0.f, az = 0.f, aw = 0.f;

  for (int base = beg; base < end; base += CHUNK) {
    int   ss[CHUNK];
    float ee[CHUNK];
    float4 hv[CHUNK];
    // stage 1: indices (independent, same cache lines)
#pragma unroll
    for (int j = 0; j < CHUNK; j++) {
      int k = base + j;                // wave-uniform validity
      ss[j] = (k < end) ? csr_src[k] : -1;
    }
    // stage 2: issue all gathers (2*CHUNK independent loads in flight)
#pragma unroll
    for (int j = 0; j < CHUNK; j++) {
      if (ss[j] >= 0) {
        float e = a_srcv[ss[j] * 4 + hh] + ad;
        ee[j] = (e >= 0.f) ? e : 0.2f * e;   // leaky relu (log2 domain)
        hv[j] = *reinterpret_cast<const float4*>(hW + (size_t)ss[j] * 256 + l * 4);
      } else {
        ee[j] = -1e30f;                      // sentinel: p -> 0, max unchanged
        hv[j] = make_float4(0.f, 0.f, 0.f, 0.f);
      }
    }
    // stage 3: serial online-softmax chain (2x v_exp, no compare/select)
#pragma unroll
    for (int j = 0; j < CHUNK; j++) {
      float e  = ee[j];
      float mn = fmaxf(m, e);
      float sc = fast_exp2(m - mn);          // 0 on first edge, 1 if max kept
      float p  = fast_exp2(e - mn);          // 1 if new max, else 2^(e-m)
      m = mn;
      ssum = fmaf(ssum, sc, p);
      ax = fmaf(ax, sc, p * hv[j].x);
      ay = fmaf(ay, sc, p * hv[j].y);
      az = fmaf(az, sc, p * hv[j].z);
      aw = fmaf(aw, sc, p * hv[j].w);
    }
  }

  // normalize (lane-local: each lane has full ssum for its head)
  float inv = 1.f / (ssum + 1e-16f);
  float o0 = ax * inv, o1 = ay * inv, o2 = az * inv, o3 = aw * inv;

  // head-mean: butterfly over the two head bits (lanes l, l^16, l^32, l^48)
#pragma unroll
  for (int mask = 16; mask <= 32; mask <<= 1) {
    o0 += __shfl_xor(o0, mask, 64);
    o1 += __shfl_xor(o1, mask, 64);
    o2 += __shfl_xor(o2, mask, 64);
    o3 += __shfl_xor(o3, mask, 64);
  }

  if (l < 16) {                        // lanes 0-15 hold cols 4l..4l+3 totals
    const float4 bv = *reinterpret_cast<const float4*>(bias + l * 4);
    float4 o;
    o.x = o0 * 0.25f + bv.x;
    o.y = o1 * 0.25f + bv.y;
    o.z = o2 * 0.25f + bv.z;
    o.w = o3 * 0.25f + bv.w;
    o.x = (o.x > 0.f) ? o.x : (expf(o.x) - 1.f);   // ELU (precise)
    o.y = (o.y > 0.f) ? o.y : (expf(o.y) - 1.f);
    o.z = (o.z > 0.f) ? o.z : (expf(o.z) - 1.f);
    o.w = (o.w > 0.f) ? o.w : (expf(o.w) - 1.f);
    *reinterpret_cast<float4*>(h_out + (size_t)node * 64 + l * 4) = o;
  }
}

// ---- atomic-free pooling (batch is sorted => groups are contiguous) ----
// Boundary detection with plain stores: each gstart entry written by exactly
// one thread.  gstart[g] = first node index with batch >= g.
__global__ void group_bounds_k(const int* __restrict__ batch, int* __restrict__ gstart,
                               int G_, int n) {
  int i = blockIdx.x * TPB + threadIdx.x;
  if (i >= n) return;
  if (i == 0) {
    int b0 = batch[0];
    for (int g = 0; g <= b0; ++g) gstart[g] = 0;
  } else {
    int bp = batch[i - 1], bc = batch[i];
    for (int g = bp + 1; g <= bc; ++g) gstart[g] = i;
  }
  if (i == n - 1) {
    int bl = batch[n - 1];
    for (int g = bl + 1; g <= G_; ++g) gstart[g] = n;
  }
}

// One block per group: deterministic coalesced mean over contiguous node range.
__global__ void pool_group_k(const float* __restrict__ h, const int* __restrict__ gstart,
                             float* __restrict__ pooled) {
  int g = blockIdx.x, t = threadIdx.x;
  int c = t & 63, sub = t >> 6;  // 4 partial accumulators per column
  int beg = gstart[g], end = gstart[g + 1];
  float s = 0.f;
  for (int i = beg + sub; i < end; i += 4) s += h[(size_t)i * 64 + c];
  __shared__ float red[4][64];
  red[sub][c] = s;
  __syncthreads();
  if (t < 64) {
    float v = red[0][t] + red[1][t] + red[2][t] + red[3][t];
    float cn = fmaxf((float)(end - beg), 1.f);
    pooled[g * 64 + t] = v / cn;
  }
}

__global__ void readout_k(const float* __restrict__ pooled,
                          const float* __restrict__ mW1, const float* __restrict__ mb1,
                          const float* __restrict__ mW2, const float* __restrict__ mb2,
                          const float* __restrict__ rW, const float* __restrict__ rb,
                          float* __restrict__ out) {
  int g = blockIdx.x, t = threadIdx.x;
  __shared__ float pm[64], r1[64], r2[64];
  pm[t] = pooled[g * 64 + t];
  __syncthreads();
  float a = mb1[t];
  for (int c = 0; c < 64; c++) a = fmaf(pm[c], mW1[c * 64 + t], a);
  a = (a > 0.f) ? a : (expf(a) - 1.f);
  r1[t] = a;
  __syncthreads();
  float b = mb2[t];
  for (int c = 0; c < 64; c++) b = fmaf(r1[c], mW2[c * 64 + t], b);
  r2[t] = b;
  __syncthreads();
  if (t == 0) {
    float o = rb[0];
    for (int c = 0; c < 64; c++) o = fmaf(r2[c], rW[c], o);
    out[g] = o;
  }
}

extern "C" void kernel_launch(void* const* d_in, const int* in_sizes, int n_in,
                              void* d_out, int out_size, void* d_ws, size_t ws_size,
                              hipStream_t stream) {
  const int* x     = (const int*)d_in[0];
  const int* ei    = (const int*)d_in[1];
  const int* batch = (const int*)d_in[2];
  const float* emb = (const float*)d_in[3];
  const float* W0  = (const float*)d_in[4];
  const float* as0 = (const float*)d_in[5];
  const float* ad0 = (const float*)d_in[6];
  const float* b0  = (const float*)d_in[7];
  const float* W1  = (const float*)d_in[8];
  const float* as1 = (const float*)d_in[9];
  const float* ad1 = (const float*)d_in[10];
  const float* b1  = (const float*)d_in[11];
  const float* W2  = (const float*)d_in[12];
  const float* as2 = (const float*)d_in[13];
  const float* ad2 = (const float*)d_in[14];
  const float* b2  = (const float*)d_in[15];
  const float* mW1 = (const float*)d_in[16];
  const float* mb1 = (const float*)d_in[17];
  const float* mW2 = (const float*)d_in[18];
  const float* mb2 = (const float*)d_in[19];
  const float* rW  = (const float*)d_in[20];
  const float* rb  = (const float*)d_in[21];
  float* out = (float*)d_out;

  const int N = in_sizes[2];       // 50000
  const int E = in_sizes[1] / 2;   // 800000
  const int TOT = E + N;           // edges incl self loops
  const int G = out_size;          // 64

  // workspace carve-up
  char* p = (char*)d_ws;
  auto alloc = [&](size_t bytes) {
    void* r = (void*)p;
    p += (bytes + 255) & ~(size_t)255;
    return r;
  };
  float* hA      = (float*)alloc((size_t)(N + 16) * 128 * 4);
  float* hWbuf   = (float*)alloc((size_t)(N + 16) * 256 * 4);
  float* hB      = (float*)alloc((size_t)(N + 16) * 64 * 4);
  float* a_srcv  = (float*)alloc((size_t)N * 4 * 4);
  float* a_dstv  = (float*)alloc((size_t)N * 4 * 4);
  int*   deg     = (int*)alloc((size_t)N * 4);
  int*   row_ptr = (int*)alloc((size_t)(N + 1) * 4);
  int*   bsum    = (int*)alloc(256 * 4);
  int*   csr     = (int*)alloc((size_t)TOT * 4);
  float* pooled  = (float*)alloc((size_t)G * 64 * 4);
  int*   gstart  = (int*)alloc((size_t)(G + 1) * 4);

  int gTOT = (TOT + TPB - 1) / TPB;
  int gN   = (N + TPB - 1) / TPB;
  int B    = gN;  // scan blocks (<=256 for N<=65536)

  // ---- CSR build (per call; ws is re-poisoned each launch) ----
  (void)hipMemsetAsync(deg, 0, (size_t)N * 4, stream);
  edge_hist_k<<<gTOT, TPB, 0, stream>>>(ei, deg, E, N);
  scan_block_k<<<B, TPB, 0, stream>>>(deg, row_ptr, bsum, N);
  scan_bsum_k<<<1, TPB, 0, stream>>>(bsum, B);
  scan_add_k<<<gN, TPB, 0, stream>>>(row_ptr, bsum, N);
  (void)hipMemsetAsync(deg, 0, (size_t)N * 4, stream);  // reuse as cursor
  edge_scatter_k<<<gTOT, TPB, 0, stream>>>(ei, row_ptr, deg, csr, E, N);

  // ---- group bounds for pooling (batch sorted => contiguous groups) ----
  group_bounds_k<<<gN, TPB, 0, stream>>>(batch, gstart, G, N);

  // ---- embedding gather ----
  gather_emb_k<<<(N * 128 + TPB - 1) / TPB, TPB, 0, stream>>>(x, emb, hA, N);

  int gGemm = (N + 15) / 16;
  int gCoef = (N * 4 + TPB - 1) / TPB;
  int gAgg  = (N + 3) / 4;   // one wave per node

  // ---- layer 0 ----
  gemm_hw_k<128><<<gGemm, TPB, 0, stream>>>(hA, W0, hWbuf, N);
  attn_coef_k<<<gCoef, TPB, 0, stream>>>(hWbuf, as0, ad0, a_srcv, a_dstv, N);
  gat_agg_k<<<gAgg, TPB, 0, stream>>>(hWbuf, a_srcv, a_dstv, row_ptr, csr, b0, hB, N);
  // ---- layer 1 ----
  gemm_hw_k<64><<<gGemm, TPB, 0, stream>>>(hB, W1, hWbuf, N);
  attn_coef_k<<<gCoef, TPB, 0, stream>>>(hWbuf, as1, ad1, a_srcv, a_dstv, N);
  gat_agg_k<<<gAgg, TPB, 0, stream>>>(hWbuf, a_srcv, a_dstv, row_ptr, csr, b1, hA, N);
  // ---- layer 2 ----
  gemm_hw_k<64><<<gGemm, TPB, 0, stream>>>(hA, W2, hWbuf, N);
  attn_coef_k<<<gCoef, TPB, 0, stream>>>(hWbuf, as2, ad2, a_srcv, a_dstv, N);
  gat_agg_k<<<gAgg, TPB, 0, stream>>>(hWbuf, a_srcv, a_dstv, row_ptr, csr, b2, hB, N);

  // ---- pooling + readout (atomic-free) ----
  pool_group_k<<<G, TPB, 0, stream>>>(hB, gstart, pooled);
  readout_k<<<G, 64, 0, stream>>>(pooled, mW1, mb1, mW2, mb2, rW, rb, out);
}